// Round 1
// baseline (389.159 us; speedup 1.0000x reference)
//
#include <hip/hip_runtime.h>
#include <math.h>

#define BB 32
#define TT 1024
#define DD 512
#define KK 64
#define OO 1024
#define EPSF 1e-12f

// ws layout (floats):
//  a      [B*T*K] = 2097152  @ 0
//  full   [B*K*D] = 1048576  @ 2097152   (xagg, then residual, then normalized; in-place)
//  sum_w  [B*K]   = 2048     @ 3145728
//  s1     [B*K]   = 2048     @ 3147776
//  scale  [B*K]   = 2048     @ 3149824

// ---------------- K1: logits = x@W + bias, softmax over k ----------------
__global__ __launch_bounds__(256) void nv_k1_softmax(
    const float* __restrict__ x, const float* __restrict__ weight,
    const float* __restrict__ bias, float* __restrict__ a_out) {
  const int b = blockIdx.y;
  const int t0 = blockIdx.x * 64;
  const int tid = threadIdx.x;
  const int tx = tid & 15, ty = tid >> 4;
  const int r0 = ty * 4, c0 = tx * 4;

  __shared__ float xs[64 * 36];   // [t_local][d_chunk], stride 36 (pad)
  __shared__ float wsm[32 * 64];  // [d_chunk][k]

  float acc[4][4];
#pragma unroll
  for (int j = 0; j < 4; ++j)
#pragma unroll
    for (int c = 0; c < 4; ++c) acc[j][c] = 0.f;

  for (int kk = 0; kk < DD; kk += 32) {
    __syncthreads();
#pragma unroll
    for (int it = 0; it < 2; ++it) {
      int f4 = it * 256 + tid;
      int r = f4 >> 3, d4 = (f4 & 7) << 2;
      float4 v = *(const float4*)(x + (size_t)(b * TT + t0 + r) * DD + kk + d4);
      *(float4*)(xs + r * 36 + d4) = v;
    }
#pragma unroll
    for (int it = 0; it < 2; ++it) {
      int f4 = it * 256 + tid;
      int i = f4 >> 4, c4 = (f4 & 15) << 2;
      float4 v = *(const float4*)(weight + (size_t)(kk + i) * KK + c4);
      *(float4*)(wsm + i * 64 + c4) = v;
    }
    __syncthreads();
#pragma unroll 8
    for (int i = 0; i < 32; ++i) {
      float av[4];
#pragma unroll
      for (int j = 0; j < 4; ++j) av[j] = xs[(r0 + j) * 36 + i];
      float4 bv = *(const float4*)(wsm + i * 64 + c0);
#pragma unroll
      for (int j = 0; j < 4; ++j) {
        acc[j][0] = fmaf(av[j], bv.x, acc[j][0]);
        acc[j][1] = fmaf(av[j], bv.y, acc[j][1]);
        acc[j][2] = fmaf(av[j], bv.z, acc[j][2]);
        acc[j][3] = fmaf(av[j], bv.w, acc[j][3]);
      }
    }
  }

  float4 bs = *(const float4*)(bias + c0);
#pragma unroll
  for (int j = 0; j < 4; ++j) {
    float l0 = acc[j][0] + bs.x, l1 = acc[j][1] + bs.y;
    float l2 = acc[j][2] + bs.z, l3 = acc[j][3] + bs.w;
    float m = fmaxf(fmaxf(l0, l1), fmaxf(l2, l3));
#pragma unroll
    for (int s = 1; s <= 8; s <<= 1) m = fmaxf(m, __shfl_xor(m, s));
    float e0 = __expf(l0 - m), e1 = __expf(l1 - m);
    float e2 = __expf(l2 - m), e3 = __expf(l3 - m);
    float sum = e0 + e1 + e2 + e3;
#pragma unroll
    for (int s = 1; s <= 8; s <<= 1) sum += __shfl_xor(sum, s);
    float inv = 1.f / sum;
    float4 o = make_float4(e0 * inv, e1 * inv, e2 * inv, e3 * inv);
    *(float4*)(a_out + (size_t)(b * TT + t0 + r0 + j) * KK + c0) = o;
  }
}

// ---------------- K2: x_agg[b,k,d] = sum_t a[b,t,k]*x[b,t,d]; fused sum_w ----------------
__global__ __launch_bounds__(256) void nv_k2_agg(
    const float* __restrict__ a_in, const float* __restrict__ x,
    float* __restrict__ xagg, float* __restrict__ sum_w) {
  const int b = blockIdx.y;
  const int d_base = blockIdx.x * 64;
  const int tid = threadIdx.x;
  const int tx = tid & 15, ty = tid >> 4;
  const int r0 = ty * 4, c0 = tx * 4;

  __shared__ float as[32 * 64];   // [tt][k]
  __shared__ float xsm[32 * 64];  // [tt][d_local]

  float acc[4][4];
#pragma unroll
  for (int j = 0; j < 4; ++j)
#pragma unroll
    for (int c = 0; c < 4; ++c) acc[j][c] = 0.f;
  float swacc = 0.f;

  for (int t0 = 0; t0 < TT; t0 += 32) {
    __syncthreads();
#pragma unroll
    for (int it = 0; it < 2; ++it) {
      int f4 = it * 256 + tid;
      int tt = f4 >> 4, c4 = (f4 & 15) << 2;
      *(float4*)(as + tt * 64 + c4) =
          *(const float4*)(a_in + (size_t)(b * TT + t0 + tt) * KK + c4);
      *(float4*)(xsm + tt * 64 + c4) =
          *(const float4*)(x + (size_t)(b * TT + t0 + tt) * DD + d_base + c4);
    }
    __syncthreads();
    if (blockIdx.x == 0 && tid < 64) {
      float s = 0.f;
#pragma unroll 8
      for (int tt = 0; tt < 32; ++tt) s += as[tt * 64 + tid];
      swacc += s;
    }
#pragma unroll 8
    for (int tt = 0; tt < 32; ++tt) {
      float4 av = *(const float4*)(as + tt * 64 + r0);
      float4 xv = *(const float4*)(xsm + tt * 64 + c0);
      float a_[4] = {av.x, av.y, av.z, av.w};
#pragma unroll
      for (int j = 0; j < 4; ++j) {
        acc[j][0] = fmaf(a_[j], xv.x, acc[j][0]);
        acc[j][1] = fmaf(a_[j], xv.y, acc[j][1]);
        acc[j][2] = fmaf(a_[j], xv.z, acc[j][2]);
        acc[j][3] = fmaf(a_[j], xv.w, acc[j][3]);
      }
    }
  }
#pragma unroll
  for (int j = 0; j < 4; ++j) {
    float4 o = make_float4(acc[j][0], acc[j][1], acc[j][2], acc[j][3]);
    *(float4*)(xagg + (size_t)(b * KK + r0 + j) * DD + d_base + c0) = o;
  }
  if (blockIdx.x == 0 && tid < 64) sum_w[b * KK + tid] = swacc;
}

// ---------------- K3a: residual + per-(b,k) sumsq ----------------
__global__ __launch_bounds__(128) void nv_k3a(
    float* __restrict__ full, const float* __restrict__ centers,
    const float* __restrict__ sum_w, float* __restrict__ s1) {
  const int k = blockIdx.x, b = blockIdx.y;
  const int tid = threadIdx.x;
  const float sw = sum_w[b * KK + k];
  float4* p = (float4*)(full + (size_t)(b * KK + k) * DD) + tid;
  float4 v = *p;
  float4 c = *((const float4*)(centers + (size_t)k * DD) + tid);
  v.x = fmaf(-sw, c.x, v.x);
  v.y = fmaf(-sw, c.y, v.y);
  v.z = fmaf(-sw, c.z, v.z);
  v.w = fmaf(-sw, c.w, v.w);
  *p = v;
  float ss = v.x * v.x + v.y * v.y + v.z * v.z + v.w * v.w;
#pragma unroll
  for (int s = 1; s <= 32; s <<= 1) ss += __shfl_xor(ss, s);
  __shared__ float red[2];
  if ((tid & 63) == 0) red[tid >> 6] = ss;
  __syncthreads();
  if (tid == 0) s1[b * KK + k] = red[0] + red[1];
}

// ---------------- K3b: per-(b,k) combined scale ----------------
__global__ __launch_bounds__(64) void nv_k3b(const float* __restrict__ s1,
                                             float* __restrict__ scale) {
  const int b = blockIdx.x, k = threadIdx.x;
  float r = s1[b * KK + k];
  float d1 = fmaxf(r, EPSF);
  float s2 = r / d1;  // == sum of squares of the intra-normalized row
#pragma unroll
  for (int s = 1; s <= 32; s <<= 1) s2 += __shfl_xor(s2, s);
  scale[b * KK + k] = rsqrtf(d1) * rsqrtf(fmaxf(s2, EPSF));
}

// ---------------- K3c: apply scale in place ----------------
__global__ __launch_bounds__(128) void nv_k3c(float* __restrict__ full,
                                              const float* __restrict__ scale) {
  const int blk = blockIdx.x;  // b*K + k
  const float sc = scale[blk];
  float4* p = (float4*)(full + (size_t)blk * DD) + threadIdx.x;
  float4 v = *p;
  v.x *= sc; v.y *= sc; v.z *= sc; v.w *= sc;
  *p = v;
}

// ---------------- zero the output (atomics accumulate into it) ----------------
__global__ void nv_kzero(float* __restrict__ out) {
  out[blockIdx.x * 256 + threadIdx.x] = 0.f;
}

// ---------------- K4: out[32,1024] = full[32,32768] @ reduc[32768,1024] ----------------
__global__ __launch_bounds__(256) void nv_k4_out(
    const float* __restrict__ full, const float* __restrict__ reduc,
    float* __restrict__ out) {
  const int c_base = blockIdx.x * 64;    // 16 col tiles
  const int r_base = blockIdx.y * 1024;  // 32 row splits
  const int tid = threadIdx.x;
  const int tx = tid & 15;        // 16 col4 groups
  const int ty = (tid >> 4) & 3;  // 4 row4 groups (within wave)
  const int tz = tid >> 6;        // wave id -> batch group of 8
  const int c0 = c_base + tx * 4;

  __shared__ float As[32 * 256];  // [b][rr]

  float acc[8][4];
#pragma unroll
  for (int bb = 0; bb < 8; ++bb)
#pragma unroll
    for (int c = 0; c < 4; ++c) acc[bb][c] = 0.f;

  for (int ch = 0; ch < 4; ++ch) {
    const int rch = r_base + ch * 256;
    __syncthreads();
#pragma unroll
    for (int it = 0; it < 8; ++it) {
      int f4 = it * 256 + tid;
      int bb = f4 >> 6, rr4 = (f4 & 63) << 2;
      *(float4*)(As + bb * 256 + rr4) =
          *(const float4*)(full + (size_t)bb * (KK * DD) + rch + rr4);
    }
    __syncthreads();
#pragma unroll 2
    for (int i = 0; i < 16; ++i) {
      const int rl = i * 16 + ty * 4;
      float wv[4][4];
#pragma unroll
      for (int j = 0; j < 4; ++j) {
        float4 w = *(const float4*)(reduc + (size_t)(rch + rl + j) * OO + c0);
        wv[j][0] = w.x; wv[j][1] = w.y; wv[j][2] = w.z; wv[j][3] = w.w;
      }
#pragma unroll
      for (int bb = 0; bb < 8; ++bb) {
        float4 a4 = *(const float4*)(As + (tz * 8 + bb) * 256 + rl);
        float a_[4] = {a4.x, a4.y, a4.z, a4.w};
#pragma unroll
        for (int j = 0; j < 4; ++j) {
          acc[bb][0] = fmaf(a_[j], wv[j][0], acc[bb][0]);
          acc[bb][1] = fmaf(a_[j], wv[j][1], acc[bb][1]);
          acc[bb][2] = fmaf(a_[j], wv[j][2], acc[bb][2]);
          acc[bb][3] = fmaf(a_[j], wv[j][3], acc[bb][3]);
        }
      }
    }
  }

  // reduce partial sums across ty (lanes ^16, ^32 within the wave), then atomic
#pragma unroll
  for (int bb = 0; bb < 8; ++bb)
#pragma unroll
    for (int c = 0; c < 4; ++c) {
      float v = acc[bb][c];
      v += __shfl_xor(v, 16);
      v += __shfl_xor(v, 32);
      if (ty == 0) atomicAdd(out + (size_t)(tz * 8 + bb) * OO + c0 + c, v);
    }
}

extern "C" void kernel_launch(void* const* d_in, const int* in_sizes, int n_in,
                              void* d_out, int out_size, void* d_ws, size_t ws_size,
                              hipStream_t stream) {
  const float* x = (const float*)d_in[0];
  const float* weight = (const float*)d_in[1];
  const float* bias = (const float*)d_in[2];
  const float* centers = (const float*)d_in[3];
  const float* reduc = (const float*)d_in[4];
  float* out = (float*)d_out;
  float* ws = (float*)d_ws;

  float* a = ws;                     // 2097152 floats
  float* full = ws + 2097152;        // 1048576 floats
  float* sum_w = ws + 3145728;       // 2048
  float* s1 = ws + 3145728 + 2048;   // 2048
  float* scale = ws + 3145728 + 4096;// 2048

  nv_k1_softmax<<<dim3(16, 32), 256, 0, stream>>>(x, weight, bias, a);
  nv_k2_agg<<<dim3(8, 32), 256, 0, stream>>>(a, x, full, sum_w);
  nv_k3a<<<dim3(64, 32), 128, 0, stream>>>(full, centers, sum_w, s1);
  nv_k3b<<<32, 64, 0, stream>>>(s1, scale);
  nv_k3c<<<2048, 128, 0, stream>>>(full, scale);
  nv_kzero<<<128, 256, 0, stream>>>(out);
  nv_k4_out<<<dim3(16, 32), 256, 0, stream>>>(full, reduc, out);
}

// Round 2
// 314.750 us; speedup vs baseline: 1.2364x; 1.2364x over previous
//
#include <hip/hip_runtime.h>
#include <math.h>

#define TT 1024
#define DD 512
#define KK 64
#define OO 1024
#define EPSF 1e-12f

// ws layout (floats), regions reused over time:
//  a      [32*1024*64] = 2097152   @ 0          (live K1 -> K2)
//  full   [32*64*512]  = 1048576   @ 0          (live K3a -> K4; overlaps dead a)
//  xaggP  [4][32*64*512] = 4194304 @ 2097152    (live K2 -> K3a)
//  outP   [64][32*1024]  = 2097152 @ 2097152    (live K4 -> K5; overlaps dead xaggP)
//  sum_w  [2048] @ 6291456 ; s1 @ +2048 ; scale @ +4096
// peak = 6291456+6144 floats ~= 25.2 MB

// ---------------- zero sum_w (atomicAdd target) ----------------
__global__ void nv_kzero(float* __restrict__ p) {
  p[blockIdx.x * 256 + threadIdx.x] = 0.f;
}

// ---------------- K1: logits = x@W + bias, softmax over k; fused sum_w ----------------
__global__ __launch_bounds__(256) void nv_k1(
    const float* __restrict__ x, const float* __restrict__ weight,
    const float* __restrict__ bias, float* __restrict__ a_out,
    float* __restrict__ sum_w) {
  const int b = blockIdx.y;
  const int t0 = blockIdx.x * 64;
  const int tid = threadIdx.x;
  const int tx = tid & 15, ty = tid >> 4;
  const int r0 = ty * 4, c0 = tx * 4;

  __shared__ float xs[64 * 68];   // [t][d], stride 68 (272B, 16B-aligned rows)
  __shared__ float wsm[64 * 64];  // [d][k]

  float acc[4][4] = {};

  for (int kk = 0; kk < DD; kk += 64) {
    __syncthreads();
#pragma unroll
    for (int it = 0; it < 4; ++it) {
      int f4 = it * 256 + tid;
      int r = f4 >> 4, d4 = (f4 & 15) << 2;
      *(float4*)(xs + r * 68 + d4) =
          *(const float4*)(x + (size_t)(b * TT + t0 + r) * DD + kk + d4);
    }
#pragma unroll
    for (int it = 0; it < 4; ++it) {
      int f4 = it * 256 + tid;
      int i = f4 >> 4, c4 = (f4 & 15) << 2;
      *(float4*)(wsm + i * 64 + c4) =
          *(const float4*)(weight + (size_t)(kk + i) * KK + c4);
    }
    __syncthreads();
#pragma unroll
    for (int i = 0; i < 64; i += 4) {
      float4 xv[4], wv[4];
#pragma unroll
      for (int j = 0; j < 4; ++j) xv[j] = *(const float4*)(xs + (r0 + j) * 68 + i);
#pragma unroll
      for (int ii = 0; ii < 4; ++ii) wv[ii] = *(const float4*)(wsm + (i + ii) * 64 + c0);
#pragma unroll
      for (int j = 0; j < 4; ++j) {
        acc[j][0] = fmaf(xv[j].x, wv[0].x, acc[j][0]);
        acc[j][1] = fmaf(xv[j].x, wv[0].y, acc[j][1]);
        acc[j][2] = fmaf(xv[j].x, wv[0].z, acc[j][2]);
        acc[j][3] = fmaf(xv[j].x, wv[0].w, acc[j][3]);
        acc[j][0] = fmaf(xv[j].y, wv[1].x, acc[j][0]);
        acc[j][1] = fmaf(xv[j].y, wv[1].y, acc[j][1]);
        acc[j][2] = fmaf(xv[j].y, wv[1].z, acc[j][2]);
        acc[j][3] = fmaf(xv[j].y, wv[1].w, acc[j][3]);
        acc[j][0] = fmaf(xv[j].z, wv[2].x, acc[j][0]);
        acc[j][1] = fmaf(xv[j].z, wv[2].y, acc[j][1]);
        acc[j][2] = fmaf(xv[j].z, wv[2].z, acc[j][2]);
        acc[j][3] = fmaf(xv[j].z, wv[2].w, acc[j][3]);
        acc[j][0] = fmaf(xv[j].w, wv[3].x, acc[j][0]);
        acc[j][1] = fmaf(xv[j].w, wv[3].y, acc[j][1]);
        acc[j][2] = fmaf(xv[j].w, wv[3].z, acc[j][2]);
        acc[j][3] = fmaf(xv[j].w, wv[3].w, acc[j][3]);
      }
    }
  }

  float4 bs = *(const float4*)(bias + c0);
  float swp0 = 0.f, swp1 = 0.f, swp2 = 0.f, swp3 = 0.f;
#pragma unroll
  for (int j = 0; j < 4; ++j) {
    float l0 = acc[j][0] + bs.x, l1 = acc[j][1] + bs.y;
    float l2 = acc[j][2] + bs.z, l3 = acc[j][3] + bs.w;
    float m = fmaxf(fmaxf(l0, l1), fmaxf(l2, l3));
#pragma unroll
    for (int s = 1; s <= 8; s <<= 1) m = fmaxf(m, __shfl_xor(m, s));
    float e0 = __expf(l0 - m), e1 = __expf(l1 - m);
    float e2 = __expf(l2 - m), e3 = __expf(l3 - m);
    float sum = e0 + e1 + e2 + e3;
#pragma unroll
    for (int s = 1; s <= 8; s <<= 1) sum += __shfl_xor(sum, s);
    float inv = 1.f / sum;
    float4 o = make_float4(e0 * inv, e1 * inv, e2 * inv, e3 * inv);
    swp0 += o.x; swp1 += o.y; swp2 += o.z; swp3 += o.w;
    *(float4*)(a_out + (size_t)(b * TT + t0 + r0 + j) * KK + c0) = o;
  }
  // block-level column sums of a-tile -> sum_w
  __syncthreads();
  *(float4*)(wsm + tid * 4) = make_float4(swp0, swp1, swp2, swp3);
  __syncthreads();
  if (tid < 64) {
    int txx = tid >> 2, cc = tid & 3;
    float s = 0.f;
#pragma unroll
    for (int g = 0; g < 16; ++g) s += wsm[(g * 16 + txx) * 4 + cc];
    atomicAdd(sum_w + b * KK + txx * 4 + cc, s);
  }
}

// ---------------- K2: xaggP[s][b][k][d] = sum_{t in split} a[b,t,k]*x[b,t,d] ----------------
__global__ __launch_bounds__(256) void nv_k2(
    const float* __restrict__ a_in, const float* __restrict__ x,
    float* __restrict__ xaggP) {
  const int d_base = blockIdx.x * 64;
  const int b = blockIdx.y;
  const int split = blockIdx.z;
  const int tid = threadIdx.x;
  const int tx = tid & 15, ty = tid >> 4;
  const int r0 = ty * 4, c0 = tx * 4;  // r0 over k, c0 over d

  __shared__ float as[64 * 64];   // [t][k]
  __shared__ float xsm[64 * 64];  // [t][d_local]

  float acc[4][4] = {};

  const int tbeg = split * 256;
  for (int t0 = tbeg; t0 < tbeg + 256; t0 += 64) {
    __syncthreads();
#pragma unroll
    for (int it = 0; it < 4; ++it) {
      int f4 = it * 256 + tid;
      int tt = f4 >> 4, c4 = (f4 & 15) << 2;
      *(float4*)(as + tt * 64 + c4) =
          *(const float4*)(a_in + (size_t)(b * TT + t0 + tt) * KK + c4);
      *(float4*)(xsm + tt * 64 + c4) =
          *(const float4*)(x + (size_t)(b * TT + t0 + tt) * DD + d_base + c4);
    }
    __syncthreads();
#pragma unroll 8
    for (int tt = 0; tt < 64; ++tt) {
      float4 av = *(const float4*)(as + tt * 64 + r0);
      float4 xv = *(const float4*)(xsm + tt * 64 + c0);
      acc[0][0] = fmaf(av.x, xv.x, acc[0][0]);
      acc[0][1] = fmaf(av.x, xv.y, acc[0][1]);
      acc[0][2] = fmaf(av.x, xv.z, acc[0][2]);
      acc[0][3] = fmaf(av.x, xv.w, acc[0][3]);
      acc[1][0] = fmaf(av.y, xv.x, acc[1][0]);
      acc[1][1] = fmaf(av.y, xv.y, acc[1][1]);
      acc[1][2] = fmaf(av.y, xv.z, acc[1][2]);
      acc[1][3] = fmaf(av.y, xv.w, acc[1][3]);
      acc[2][0] = fmaf(av.z, xv.x, acc[2][0]);
      acc[2][1] = fmaf(av.z, xv.y, acc[2][1]);
      acc[2][2] = fmaf(av.z, xv.z, acc[2][2]);
      acc[2][3] = fmaf(av.z, xv.w, acc[2][3]);
      acc[3][0] = fmaf(av.w, xv.x, acc[3][0]);
      acc[3][1] = fmaf(av.w, xv.y, acc[3][1]);
      acc[3][2] = fmaf(av.w, xv.z, acc[3][2]);
      acc[3][3] = fmaf(av.w, xv.w, acc[3][3]);
    }
  }
#pragma unroll
  for (int j = 0; j < 4; ++j) {
    *(float4*)(xaggP + ((size_t)((split * 32 + b) * KK + r0 + j)) * DD + d_base + c0) =
        make_float4(acc[j][0], acc[j][1], acc[j][2], acc[j][3]);
  }
}

// ---------------- K3a: sum partials, residual vs centers, per-(b,k) sumsq ----------------
__global__ __launch_bounds__(128) void nv_k3a(
    const float* __restrict__ xaggP, float* __restrict__ full,
    const float* __restrict__ centers, const float* __restrict__ sum_w,
    float* __restrict__ s1) {
  const int k = blockIdx.x, b = blockIdx.y;
  const int tid = threadIdx.x;
  const float sw = sum_w[b * KK + k];
  float4 v = make_float4(0.f, 0.f, 0.f, 0.f);
#pragma unroll
  for (int sp = 0; sp < 4; ++sp) {
    float4 p = *((const float4*)(xaggP + (size_t)((sp * 32 + b) * KK + k) * DD) + tid);
    v.x += p.x; v.y += p.y; v.z += p.z; v.w += p.w;
  }
  float4 c = *((const float4*)(centers + (size_t)k * DD) + tid);
  v.x = fmaf(-sw, c.x, v.x);
  v.y = fmaf(-sw, c.y, v.y);
  v.z = fmaf(-sw, c.z, v.z);
  v.w = fmaf(-sw, c.w, v.w);
  *((float4*)(full + (size_t)(b * KK + k) * DD) + tid) = v;
  float ss = v.x * v.x + v.y * v.y + v.z * v.z + v.w * v.w;
#pragma unroll
  for (int s = 1; s <= 32; s <<= 1) ss += __shfl_xor(ss, s);
  __shared__ float red[2];
  if ((tid & 63) == 0) red[tid >> 6] = ss;
  __syncthreads();
  if (tid == 0) s1[b * KK + k] = red[0] + red[1];
}

// ---------------- K3b: per-(b,k) combined scale ----------------
__global__ __launch_bounds__(64) void nv_k3b(const float* __restrict__ s1,
                                             float* __restrict__ scale) {
  const int b = blockIdx.x, k = threadIdx.x;
  float r = s1[b * KK + k];
  float d1 = fmaxf(r, EPSF);
  float s2 = r / d1;
#pragma unroll
  for (int s = 1; s <= 32; s <<= 1) s2 += __shfl_xor(s2, s);
  scale[b * KK + k] = rsqrtf(d1) * rsqrtf(fmaxf(s2, EPSF));
}

// ---------------- K3c: apply scale in place ----------------
__global__ __launch_bounds__(128) void nv_k3c(float* __restrict__ full,
                                              const float* __restrict__ scale) {
  const int blk = blockIdx.x;  // b*K + k
  const float sc = scale[blk];
  float4* p = (float4*)(full + (size_t)blk * DD) + threadIdx.x;
  float4 v = *p;
  v.x *= sc; v.y *= sc; v.z *= sc; v.w *= sc;
  *p = v;
}

// ---------------- K4: outP[split][32][1024] partial GEMM ----------------
__global__ __launch_bounds__(256) void nv_k4(
    const float* __restrict__ full, const float* __restrict__ reduc,
    float* __restrict__ outP) {
  const int c_base = blockIdx.x * 64;   // 16 col tiles
  const int r_base = blockIdx.y * 512;  // 64 row splits
  const int tid = threadIdx.x;
  const int tx = tid & 15;        // 16 col4 groups
  const int ty = (tid >> 4) & 3;  // 4 row groups within wave
  const int tz = tid >> 6;        // wave -> batch group of 8
  const int c0 = c_base + tx * 4;

  __shared__ float As[32 * 256];  // [b][row_local]

  float acc[8][4] = {};

  for (int ch = 0; ch < 2; ++ch) {
    const int rch = r_base + ch * 256;
    __syncthreads();
#pragma unroll
    for (int it = 0; it < 8; ++it) {
      int f4 = it * 256 + tid;
      int bb = f4 >> 6, rr4 = (f4 & 63) << 2;
      *(float4*)(As + bb * 256 + rr4) =
          *(const float4*)(full + (size_t)bb * 32768 + rch + rr4);
    }
    __syncthreads();
#pragma unroll 4
    for (int i = 0; i < 16; ++i) {
      const int rl = i * 16 + ty * 4;
      float wv[4][4];
#pragma unroll
      for (int j = 0; j < 4; ++j) {
        float4 w = *(const float4*)(reduc + (size_t)(rch + rl + j) * OO + c0);
        wv[j][0] = w.x; wv[j][1] = w.y; wv[j][2] = w.z; wv[j][3] = w.w;
      }
#pragma unroll
      for (int bb = 0; bb < 8; ++bb) {
        float4 a4 = *(const float4*)(As + (tz * 8 + bb) * 256 + rl);
        float a_[4] = {a4.x, a4.y, a4.z, a4.w};
#pragma unroll
        for (int j = 0; j < 4; ++j) {
          acc[bb][0] = fmaf(a_[j], wv[j][0], acc[bb][0]);
          acc[bb][1] = fmaf(a_[j], wv[j][1], acc[bb][1]);
          acc[bb][2] = fmaf(a_[j], wv[j][2], acc[bb][2]);
          acc[bb][3] = fmaf(a_[j], wv[j][3], acc[bb][3]);
        }
      }
    }
  }

  // reduce over ty (lanes ^16, ^32) then write partials (no atomics)
#pragma unroll
  for (int bb = 0; bb < 8; ++bb) {
    float4 v = make_float4(acc[bb][0], acc[bb][1], acc[bb][2], acc[bb][3]);
    v.x += __shfl_xor(v.x, 16); v.x += __shfl_xor(v.x, 32);
    v.y += __shfl_xor(v.y, 16); v.y += __shfl_xor(v.y, 32);
    v.z += __shfl_xor(v.z, 16); v.z += __shfl_xor(v.z, 32);
    v.w += __shfl_xor(v.w, 16); v.w += __shfl_xor(v.w, 32);
    if (ty == 0) {
      *(float4*)(outP + (size_t)(blockIdx.y * 32 + tz * 8 + bb) * OO + c0) = v;
    }
  }
}

// ---------------- K5: out = sum over 64 row-splits of outP ----------------
__global__ __launch_bounds__(256) void nv_k5(const float* __restrict__ outP,
                                             float* __restrict__ out) {
  const int idx = blockIdx.x * 256 + threadIdx.x;  // 0..32767
  float s = 0.f;
#pragma unroll 8
  for (int sp = 0; sp < 64; ++sp) s += outP[(size_t)sp * 32768 + idx];
  out[idx] = s;
}

extern "C" void kernel_launch(void* const* d_in, const int* in_sizes, int n_in,
                              void* d_out, int out_size, void* d_ws, size_t ws_size,
                              hipStream_t stream) {
  const float* x = (const float*)d_in[0];
  const float* weight = (const float*)d_in[1];
  const float* bias = (const float*)d_in[2];
  const float* centers = (const float*)d_in[3];
  const float* reduc = (const float*)d_in[4];
  float* out = (float*)d_out;
  float* ws = (float*)d_ws;

  float* a = ws;                      // [0, 2M)
  float* full = ws;                   // [0, 1M)  (after a is dead)
  float* xaggP = ws + 2097152;        // [2M, 6M)
  float* outP = ws + 2097152;         // [2M, 4M) (after xaggP is dead)
  float* sum_w = ws + 6291456;
  float* s1 = sum_w + 2048;
  float* scale = sum_w + 4096;

  nv_kzero<<<8, 256, 0, stream>>>(sum_w);
  nv_k1<<<dim3(16, 32), 256, 0, stream>>>(x, weight, bias, a, sum_w);
  nv_k2<<<dim3(8, 32, 4), 256, 0, stream>>>(a, x, xaggP);
  nv_k3a<<<dim3(64, 32), 128, 0, stream>>>(xaggP, full, centers, sum_w, s1);
  nv_k3b<<<32, 64, 0, stream>>>(s1, scale);
  nv_k3c<<<2048, 128, 0, stream>>>(full, scale);
  nv_k4<<<dim3(16, 64), 256, 0, stream>>>(full, reduc, outP);
  nv_k5<<<128, 256, 0, stream>>>(outP, out);
}

// Round 3
// 291.314 us; speedup vs baseline: 1.3359x; 1.0805x over previous
//
#include <hip/hip_runtime.h>
#include <math.h>

#define TT 1024
#define DD 512
#define KK 64
#define OO 1024
#define EPSF 1e-12f

typedef __attribute__((ext_vector_type(8))) short bf16x8;
typedef __attribute__((ext_vector_type(4))) float f32x4;

__device__ __forceinline__ ushort f2bf(float f) {
  unsigned u = __float_as_uint(f);
  u = (u + 0x7FFFu + ((u >> 16) & 1u)) >> 16;
  return (ushort)u;
}
__device__ __forceinline__ float bf2f(ushort h) {
  unsigned u = ((unsigned)h) << 16;
  return __uint_as_float(u);
}

// ws layout (float units):
//  aT    bf16[32][64][1024] = 2M ushorts  @ [0, 1M)
//  full  f32 [32*64*512]    = 1M floats   @ [1M, 2M)
//  xaggP f32 [2][32*64*512] = 2M floats   @ [2M, 4M)
//  outP  f32 [64][32*1024]  = 2M floats   @ [4M, 6M)
//  whT   bf16[64][512]      = 32768 ushorts = 16K floats @ 6M
//  sum_w @ 6M+16K ; s1 +2048 ; scale +4096

__global__ void nv_kzero(float* __restrict__ p) {
  p[blockIdx.x * 256 + threadIdx.x] = 0.f;
}

// ---------------- K0w: whT[k][d] bf16 <- weight[d][k] f32 ----------------
__global__ __launch_bounds__(256) void nv_k0w(const float* __restrict__ w,
                                              ushort* __restrict__ whT) {
  int idx = blockIdx.x * 256 + threadIdx.x;  // 32768
  int d = idx >> 6, k = idx & 63;
  whT[(size_t)k * DD + d] = f2bf(w[idx]);
}

// ---------------- K1: a = softmax(x@W + bias); writes aT[b][k][t] bf16 + sum_w ----------------
__global__ __launch_bounds__(256) void nv_k1(
    const float* __restrict__ x, const ushort* __restrict__ whT,
    const float* __restrict__ bias, ushort* __restrict__ aT,
    float* __restrict__ sum_w) {
  const int b = blockIdx.y, t0 = blockIdx.x * 128;
  const int tid = threadIdx.x;
  const int wave = tid >> 6, lane = tid & 63, l15 = lane & 15, q = lane >> 4;

  __shared__ ushort xs[128 * 64];  // A-tile [t][d-chunk], granule-swizzled g^(t&7)
  __shared__ ushort wsm[64 * 64];  // B-tile [k][d-chunk], granule-swizzled g^(k&7)

  f32x4 acc[2][4];
#pragma unroll
  for (int mt = 0; mt < 2; ++mt)
#pragma unroll
    for (int nt = 0; nt < 4; ++nt)
#pragma unroll
      for (int r = 0; r < 4; ++r) acc[mt][nt][r] = 0.f;

  for (int dc = 0; dc < DD; dc += 64) {
    __syncthreads();
    // stage A (x fp32 -> bf16), 1024 granules of 16B
#pragma unroll
    for (int it = 0; it < 4; ++it) {
      int gid = it * 256 + tid;
      int t = gid >> 3, g = gid & 7;
      const float* px = x + ((size_t)(b * TT + t0 + t) * DD + dc + g * 8);
      float4 v0 = *(const float4*)px;
      float4 v1 = *(const float4*)(px + 4);
      bf16x8 pk;
      pk[0] = (short)f2bf(v0.x); pk[1] = (short)f2bf(v0.y);
      pk[2] = (short)f2bf(v0.z); pk[3] = (short)f2bf(v0.w);
      pk[4] = (short)f2bf(v1.x); pk[5] = (short)f2bf(v1.y);
      pk[6] = (short)f2bf(v1.z); pk[7] = (short)f2bf(v1.w);
      *(bf16x8*)(xs + t * 64 + ((g ^ (t & 7)) << 3)) = pk;
    }
    // stage B from whT[k][d], 512 granules
#pragma unroll
    for (int it = 0; it < 2; ++it) {
      int gid = it * 256 + tid;
      int k = gid >> 3, g = gid & 7;
      bf16x8 v = *(const bf16x8*)(whT + (size_t)k * DD + dc + g * 8);
      *(bf16x8*)(wsm + k * 64 + ((g ^ (k & 7)) << 3)) = v;
    }
    __syncthreads();
#pragma unroll
    for (int kc = 0; kc < 2; ++kc) {
      int gq = kc * 4 + q;
      bf16x8 bf[4];
#pragma unroll
      for (int nt = 0; nt < 4; ++nt) {
        int k = nt * 16 + l15;
        bf[nt] = *(const bf16x8*)(wsm + k * 64 + ((gq ^ (k & 7)) << 3));
      }
#pragma unroll
      for (int mt = 0; mt < 2; ++mt) {
        int t = wave * 32 + mt * 16 + l15;
        bf16x8 af = *(const bf16x8*)(xs + t * 64 + ((gq ^ (t & 7)) << 3));
#pragma unroll
        for (int nt = 0; nt < 4; ++nt)
          acc[mt][nt] = __builtin_amdgcn_mfma_f32_16x16x32_bf16(af, bf[nt], acc[mt][nt], 0, 0, 0);
      }
    }
  }

  // epilogue: softmax over k (row = t), fp32
  float bia[4];
#pragma unroll
  for (int nt = 0; nt < 4; ++nt) bia[nt] = bias[nt * 16 + l15];

  ushort au[2][4][4];
  float sw[4] = {0.f, 0.f, 0.f, 0.f};
#pragma unroll
  for (int mt = 0; mt < 2; ++mt)
#pragma unroll
    for (int r = 0; r < 4; ++r) {
      float l[4];
#pragma unroll
      for (int nt = 0; nt < 4; ++nt) l[nt] = acc[mt][nt][r] + bia[nt];
      float m = fmaxf(fmaxf(l[0], l[1]), fmaxf(l[2], l[3]));
#pragma unroll
      for (int s = 1; s <= 8; s <<= 1) m = fmaxf(m, __shfl_xor(m, s));
      float e[4];
#pragma unroll
      for (int nt = 0; nt < 4; ++nt) e[nt] = __expf(l[nt] - m);
      float ssum = e[0] + e[1] + e[2] + e[3];
#pragma unroll
      for (int s = 1; s <= 8; s <<= 1) ssum += __shfl_xor(ssum, s);
      float inv = 1.f / ssum;
#pragma unroll
      for (int nt = 0; nt < 4; ++nt) {
        ushort u = f2bf(e[nt] * inv);
        au[mt][nt][r] = u;
        sw[nt] += bf2f(u);  // sum_w consistent with the bf16 a used downstream
      }
    }
  // sum_w: reduce over q-groups, one atomic per (wave, nt)
#pragma unroll
  for (int nt = 0; nt < 4; ++nt) {
    float s = sw[nt];
    s += __shfl_xor(s, 16);
    s += __shfl_xor(s, 32);
    if (q == 0) atomicAdd(sum_w + b * KK + nt * 16 + l15, s);
  }
  // transpose a-tile -> aT[b][k][t] via LDS (reuse xs: [64 k][128 t], swizzle tg^(k&15))
  __syncthreads();
#pragma unroll
  for (int mt = 0; mt < 2; ++mt)
#pragma unroll
    for (int nt = 0; nt < 4; ++nt)
#pragma unroll
      for (int r = 0; r < 4; ++r) {
        int k = nt * 16 + l15;
        int t = wave * 32 + mt * 16 + q * 4 + r;
        int tg = t >> 3;
        xs[k * 128 + ((tg ^ l15) << 3) + (t & 7)] = au[mt][nt][r];
      }
  __syncthreads();
#pragma unroll
  for (int it = 0; it < 4; ++it) {
    int gid = it * 256 + tid;
    int k = gid >> 4, g = gid & 15;
    bf16x8 v = *(const bf16x8*)(xs + k * 128 + ((g ^ (k & 15)) << 3));
    *(bf16x8*)(aT + (size_t)(b * KK + k) * TT + t0 + g * 8) = v;
  }
}

// ---------------- K2: xaggP[tsp][b][k][d] = sum_{t in half} a[t][k] * x[t][d] (MFMA) ----------------
__global__ __launch_bounds__(256) void nv_k2(
    const ushort* __restrict__ aT, const float* __restrict__ x,
    float* __restrict__ xaggP) {
  const int dsp = blockIdx.x;  // 8 d-tiles of 64
  const int b = blockIdx.y;
  const int tsp = blockIdx.z;  // 2 t-halves
  const int tid = threadIdx.x;
  const int wave = tid >> 6, lane = tid & 63, l15 = lane & 15, q = lane >> 4;
  const int d0 = dsp * 64;

  __shared__ ushort asx[64 * 64];  // aT tile [k][t-chunk], swizzle g^(k&7)
  __shared__ ushort xsT[64 * 64];  // x^T tile [d][t-chunk], swizzle tg^((d^(d>>3))&7)

  f32x4 acc[4];
#pragma unroll
  for (int nt = 0; nt < 4; ++nt)
#pragma unroll
    for (int r = 0; r < 4; ++r) acc[nt][r] = 0.f;

  for (int tc = 0; tc < 8; ++tc) {
    const int t0 = tsp * 512 + tc * 64;
    __syncthreads();
    // stage aT tile (b128 granules, already bf16)
#pragma unroll
    for (int it = 0; it < 2; ++it) {
      int gid = it * 256 + tid;
      int k = gid >> 3, g = gid & 7;
      bf16x8 v = *(const bf16x8*)(aT + (size_t)(b * KK + k) * TT + t0 + g * 8);
      *(bf16x8*)(asx + k * 64 + ((g ^ (k & 7)) << 3)) = v;
    }
    // stage x transposed + converted: [d][t]
#pragma unroll
    for (int it = 0; it < 4; ++it) {
      int fid = it * 256 + tid;
      int t = fid >> 4, dq = fid & 15;
      float4 v = *(const float4*)(x + (size_t)(b * TT + t0 + t) * DD + d0 + dq * 4);
      int tg = t >> 3;
      float vv[4] = {v.x, v.y, v.z, v.w};
#pragma unroll
      for (int i = 0; i < 4; ++i) {
        int d = dq * 4 + i;
        int pos = tg ^ ((d ^ (d >> 3)) & 7);
        xsT[d * 64 + (pos << 3) + (t & 7)] = f2bf(vv[i]);
      }
    }
    __syncthreads();
#pragma unroll
    for (int kc = 0; kc < 2; ++kc) {
      int gq = kc * 4 + q;
      int k = wave * 16 + l15;
      bf16x8 af = *(const bf16x8*)(asx + k * 64 + ((gq ^ (k & 7)) << 3));
#pragma unroll
      for (int nt = 0; nt < 4; ++nt) {
        int d = nt * 16 + l15;
        int pos = gq ^ ((d ^ (d >> 3)) & 7);
        bf16x8 bf = *(const bf16x8*)(xsT + d * 64 + (pos << 3));
        acc[nt] = __builtin_amdgcn_mfma_f32_16x16x32_bf16(af, bf, acc[nt], 0, 0, 0);
      }
    }
  }
  // C layout: row k = wave*16 + q*4 + r, col d = d0 + nt*16 + l15
#pragma unroll
  for (int nt = 0; nt < 4; ++nt)
#pragma unroll
    for (int r = 0; r < 4; ++r) {
      int k = wave * 16 + q * 4 + r;
      xaggP[(size_t)((tsp * 32 + b) * KK + k) * DD + d0 + nt * 16 + l15] = acc[nt][r];
    }
}

// ---------------- K3a: sum 2 partials, residual vs centers, per-(b,k) sumsq ----------------
__global__ __launch_bounds__(128) void nv_k3a(
    const float* __restrict__ xaggP, float* __restrict__ full,
    const float* __restrict__ centers, const float* __restrict__ sum_w,
    float* __restrict__ s1) {
  const int k = blockIdx.x, b = blockIdx.y;
  const int tid = threadIdx.x;
  const float sw = sum_w[b * KK + k];
  float4 v = make_float4(0.f, 0.f, 0.f, 0.f);
#pragma unroll
  for (int sp = 0; sp < 2; ++sp) {
    float4 p = *((const float4*)(xaggP + (size_t)((sp * 32 + b) * KK + k) * DD) + tid);
    v.x += p.x; v.y += p.y; v.z += p.z; v.w += p.w;
  }
  float4 c = *((const float4*)(centers + (size_t)k * DD) + tid);
  v.x = fmaf(-sw, c.x, v.x);
  v.y = fmaf(-sw, c.y, v.y);
  v.z = fmaf(-sw, c.z, v.z);
  v.w = fmaf(-sw, c.w, v.w);
  *((float4*)(full + (size_t)(b * KK + k) * DD) + tid) = v;
  float ss = v.x * v.x + v.y * v.y + v.z * v.z + v.w * v.w;
#pragma unroll
  for (int s = 1; s <= 32; s <<= 1) ss += __shfl_xor(ss, s);
  __shared__ float red[2];
  if ((tid & 63) == 0) red[tid >> 6] = ss;
  __syncthreads();
  if (tid == 0) s1[b * KK + k] = red[0] + red[1];
}

// ---------------- K3b: per-(b,k) combined scale ----------------
__global__ __launch_bounds__(64) void nv_k3b(const float* __restrict__ s1,
                                             float* __restrict__ scale) {
  const int b = blockIdx.x, k = threadIdx.x;
  float r = s1[b * KK + k];
  float d1 = fmaxf(r, EPSF);
  float s2 = r / d1;
#pragma unroll
  for (int s = 1; s <= 32; s <<= 1) s2 += __shfl_xor(s2, s);
  scale[b * KK + k] = rsqrtf(d1) * rsqrtf(fmaxf(s2, EPSF));
}

// ---------------- K3c: apply scale in place ----------------
__global__ __launch_bounds__(128) void nv_k3c(float* __restrict__ full,
                                              const float* __restrict__ scale) {
  const int blk = blockIdx.x;  // b*K + k
  const float sc = scale[blk];
  float4* p = (float4*)(full + (size_t)blk * DD) + threadIdx.x;
  float4 v = *p;
  v.x *= sc; v.y *= sc; v.z *= sc; v.w *= sc;
  *p = v;
}

// ---------------- K4: outP[split][32][1024] partial GEMM (fp32) ----------------
__global__ __launch_bounds__(256) void nv_k4(
    const float* __restrict__ full, const float* __restrict__ reduc,
    float* __restrict__ outP) {
  const int c_base = blockIdx.x * 64;   // 16 col tiles
  const int r_base = blockIdx.y * 512;  // 64 row splits
  const int tid = threadIdx.x;
  const int tx = tid & 15;
  const int ty = (tid >> 4) & 3;
  const int tz = tid >> 6;
  const int c0 = c_base + tx * 4;

  __shared__ float As[32 * 256];

  float acc[8][4] = {};

  for (int ch = 0; ch < 2; ++ch) {
    const int rch = r_base + ch * 256;
    __syncthreads();
#pragma unroll
    for (int it = 0; it < 8; ++it) {
      int f4 = it * 256 + tid;
      int bb = f4 >> 6, rr4 = (f4 & 63) << 2;
      *(float4*)(As + bb * 256 + rr4) =
          *(const float4*)(full + (size_t)bb * 32768 + rch + rr4);
    }
    __syncthreads();
#pragma unroll 4
    for (int i = 0; i < 16; ++i) {
      const int rl = i * 16 + ty * 4;
      float wv[4][4];
#pragma unroll
      for (int j = 0; j < 4; ++j) {
        float4 w = *(const float4*)(reduc + (size_t)(rch + rl + j) * OO + c0);
        wv[j][0] = w.x; wv[j][1] = w.y; wv[j][2] = w.z; wv[j][3] = w.w;
      }
#pragma unroll
      for (int bb = 0; bb < 8; ++bb) {
        float4 a4 = *(const float4*)(As + (tz * 8 + bb) * 256 + rl);
        float a_[4] = {a4.x, a4.y, a4.z, a4.w};
#pragma unroll
        for (int j = 0; j < 4; ++j) {
          acc[bb][0] = fmaf(a_[j], wv[j][0], acc[bb][0]);
          acc[bb][1] = fmaf(a_[j], wv[j][1], acc[bb][1]);
          acc[bb][2] = fmaf(a_[j], wv[j][2], acc[bb][2]);
          acc[bb][3] = fmaf(a_[j], wv[j][3], acc[bb][3]);
        }
      }
    }
  }

#pragma unroll
  for (int bb = 0; bb < 8; ++bb) {
    float4 v = make_float4(acc[bb][0], acc[bb][1], acc[bb][2], acc[bb][3]);
    v.x += __shfl_xor(v.x, 16); v.x += __shfl_xor(v.x, 32);
    v.y += __shfl_xor(v.y, 16); v.y += __shfl_xor(v.y, 32);
    v.z += __shfl_xor(v.z, 16); v.z += __shfl_xor(v.z, 32);
    v.w += __shfl_xor(v.w, 16); v.w += __shfl_xor(v.w, 32);
    if (ty == 0) {
      *(float4*)(outP + (size_t)(blockIdx.y * 32 + tz * 8 + bb) * OO + c0) = v;
    }
  }
}

// ---------------- K5: out = sum over 64 row-splits of outP ----------------
__global__ __launch_bounds__(256) void nv_k5(const float* __restrict__ outP,
                                             float* __restrict__ out) {
  const int idx = blockIdx.x * 256 + threadIdx.x;
  float s = 0.f;
#pragma unroll 8
  for (int sp = 0; sp < 64; ++sp) s += outP[(size_t)sp * 32768 + idx];
  out[idx] = s;
}

extern "C" void kernel_launch(void* const* d_in, const int* in_sizes, int n_in,
                              void* d_out, int out_size, void* d_ws, size_t ws_size,
                              hipStream_t stream) {
  const float* x = (const float*)d_in[0];
  const float* weight = (const float*)d_in[1];
  const float* bias = (const float*)d_in[2];
  const float* centers = (const float*)d_in[3];
  const float* reduc = (const float*)d_in[4];
  float* out = (float*)d_out;
  float* ws = (float*)d_ws;

  ushort* aT = (ushort*)ws;              // 2M ushorts @ [0,1M) floats
  float* full = ws + 1048576;            // [1M,2M)
  float* xaggP = ws + 2097152;           // [2M,4M)
  float* outP = ws + 4194304;            // [4M,6M)
  ushort* whT = (ushort*)(ws + 6291456); // 32768 ushorts
  float* sum_w = ws + 6291456 + 16384;
  float* s1 = sum_w + 2048;
  float* scale = sum_w + 4096;

  nv_kzero<<<8, 256, 0, stream>>>(sum_w);
  nv_k0w<<<128, 256, 0, stream>>>(weight, whT);
  nv_k1<<<dim3(8, 32), 256, 0, stream>>>(x, whT, bias, aT, sum_w);
  nv_k2<<<dim3(8, 32, 2), 256, 0, stream>>>(aT, x, xaggP);
  nv_k3a<<<dim3(64, 32), 128, 0, stream>>>(xaggP, full, centers, sum_w, s1);
  nv_k3b<<<32, 64, 0, stream>>>(s1, scale);
  nv_k3c<<<2048, 128, 0, stream>>>(full, scale);
  nv_k4<<<dim3(16, 64), 256, 0, stream>>>(full, reduc, outP);
  nv_k5<<<128, 256, 0, stream>>>(outP, out);
}